// Round 4
// baseline (868.485 us; speedup 1.0000x reference)
//
#include <hip/hip_runtime.h>
#include <hip/hip_bf16.h>

#define Bc 8
#define Nc 256
#define Dc 256
#define Hc 16
#define DKc 16
#define MSc 16
#define FFc 512

// All tensors (inputs AND output) are fp32, matching the reference's
// jnp.float32 setup. [R1/R3 evidence: bf16-reading inputs -> NaN;
// bf16-writing output -> finite 6.39 garbage; fp32 detect flag fired.]

// Projection emb(b,n,:) @ W -> head layout out[((b*H+h)*N + n)*DK + dk]
__global__ void proj_kernel(const float* __restrict__ emb, const float* __restrict__ W,
                            float* __restrict__ out) {
    int row = blockIdx.x;            // b*N + n
    int b = row >> 8, n = row & 255;
    int hd = threadIdx.x;            // h*DK + dk
    __shared__ float se[Dc];
    se[hd] = emb[row * Dc + hd];
    __syncthreads();
    float acc = 0.f;
#pragma unroll 8
    for (int d = 0; d < Dc; ++d)
        acc += se[d] * W[d * (Hc * DKc) + hd];
    int h = hd >> 4, dk = hd & 15;
    out[((b * Hc + h) * Nc + n) * DKc + dk] = acc;
}

// Fused: dot -> per-head 2->MS->1 MLP -> softmax over cols -> @V
// One block per (b,h,r); thread = column c.
__global__ void attn_kernel(const float* __restrict__ Q, const float* __restrict__ K,
                            const float* __restrict__ V, const float* __restrict__ cost,
                            const float* __restrict__ m1w, const float* __restrict__ m1b,
                            const float* __restrict__ m2w, const float* __restrict__ m2b,
                            float* __restrict__ out_concat, int tr) {
    int idx = blockIdx.x;            // (b*H + h)*N + r
    int r = idx & 255;
    int bh = idx >> 8;
    int h = bh & 15;
    int b = bh >> 4;
    int c = threadIdx.x;

    __shared__ float sq[DKc];
    __shared__ float red[256];
    __shared__ float wsh[256];
    __shared__ float sm1w[32], sm1b[16], sm2w[16], sm2b;

    if (c < DKc) sq[c] = Q[(bh * Nc + r) * DKc + c];
    if (c >= 32 && c < 64)        sm1w[c - 32] = m1w[h * 32 + (c - 32)];
    else if (c >= 64 && c < 80)   sm1b[c - 64] = m1b[h * 16 + (c - 64)];
    else if (c >= 80 && c < 96)   sm2w[c - 80] = m2w[h * 16 + (c - 80)];
    else if (c == 96)             sm2b = m2b[h];
    __syncthreads();

    const float* kp = K + (bh * Nc + c) * DKc;
    float dot = 0.f;
#pragma unroll
    for (int i = 0; i < DKc; ++i) dot += sq[i] * kp[i];
    dot *= 0.25f;  // 1/sqrt(DK)

    float cost_v = tr ? cost[(b * Nc + c) * Nc + r]
                      : cost[(b * Nc + r) * Nc + c];

    float mixed = sm2b;
#pragma unroll
    for (int m = 0; m < MSc; ++m) {
        float t = dot * sm1w[m] + cost_v * sm1w[16 + m] + sm1b[m];
        t = fmaxf(t, 0.f);
        mixed += t * sm2w[m];
    }

    // softmax over the 256 columns
    red[c] = mixed;
    __syncthreads();
    for (int s = 128; s > 0; s >>= 1) {
        if (c < s) red[c] = fmaxf(red[c], red[c + s]);
        __syncthreads();
    }
    float mx = red[0];
    __syncthreads();
    float e = __expf(mixed - mx);
    red[c] = e;
    __syncthreads();
    for (int s = 128; s > 0; s >>= 1) {
        if (c < s) red[c] += red[c + s];
        __syncthreads();
    }
    float w = e / red[0];
    wsh[c] = w;
    __syncthreads();

    // PV: partials over 16-column chunks, then reduce 16 chunks per dk
    int dk = c & 15, chunk = c >> 4;
    const float* vp = V + (bh * Nc + chunk * 16) * DKc + dk;
    float part = 0.f;
#pragma unroll
    for (int j = 0; j < 16; ++j) part += wsh[chunk * 16 + j] * vp[j * DKc];
    red[c] = part;
    __syncthreads();
    if (c < DKc) {
        float o = 0.f;
#pragma unroll
        for (int ch = 0; ch < 16; ++ch) o += red[ch * 16 + c];
        out_concat[(b * Nc + r) * (Hc * DKc) + h * DKc + c] = o;
    }
}

// out[row][j] = sum_k A[row][k]*W[k][j] + bias[j]  (+relu) (+f32 residual)
// blockDim.x == Nout; dynamic LDS = Kdim floats
__global__ void gemm_kernel(const float* __restrict__ A, const float* __restrict__ W,
                            const float* __restrict__ bias, const float* __restrict__ res,
                            float* __restrict__ out, int Kdim, int Nout, int do_relu) {
    int row = blockIdx.x;
    int j = threadIdx.x;
    extern __shared__ float sA[];
    for (int i = j; i < Kdim; i += blockDim.x) sA[i] = A[(size_t)row * Kdim + i];
    __syncthreads();
    float acc = 0.f;
#pragma unroll 8
    for (int k = 0; k < Kdim; ++k) acc += sA[k] * W[k * Nout + j];
    acc += bias[j];
    if (do_relu) acc = fmaxf(acc, 0.f);
    if (res) acc += res[(size_t)row * Nout + j];
    out[(size_t)row * Nout + j] = acc;
}

// InstanceNorm over n (axis=1) per (b, d); optional f32 residual; fp32 out
__global__ void inorm_kernel(const float* __restrict__ x, const float* __restrict__ res,
                             const float* __restrict__ scale, const float* __restrict__ bias,
                             float* __restrict__ out) {
    int b = blockIdx.x;
    int d = threadIdx.x;
    const float* xp = x + (size_t)b * Nc * Dc + d;
    const float* rp = res ? res + (size_t)b * Nc * Dc + d : nullptr;
    float sum = 0.f, sumsq = 0.f;
    for (int n = 0; n < Nc; ++n) {
        float v = xp[n * Dc];
        if (rp) v += rp[n * Dc];
        sum += v;
        sumsq += v * v;
    }
    float mean = sum * (1.f / Nc);
    float var = sumsq * (1.f / Nc) - mean * mean;
    float inv = rsqrtf(var + 1e-5f);
    float s = scale[d];
    float bi = bias[d];
    for (int n = 0; n < Nc; ++n) {
        float v = xp[n * Dc];
        if (rp) v += rp[n * Dc];
        out[(size_t)b * Nc * Dc + n * Dc + d] = (v - mean) * inv * s + bi;
    }
}

extern "C" void kernel_launch(void* const* d_in, const int* in_sizes, int n_in,
                              void* d_out, int out_size, void* d_ws, size_t ws_size,
                              hipStream_t stream) {
    const float* row_emb = (const float*)d_in[0];
    const float* col_emb = (const float*)d_in[1];
    const float* cost    = (const float*)d_in[2];
    float* out = (float*)d_out;          // reference output dtype = float32
    float* ws = (float*)d_ws;

    const size_t SZ = (size_t)Bc * Nc * Dc;   // 524288
    // 4-buffer reuse plan (total 4*SZ floats = 8.39 MB):
    //  buf0: Q    -> x1  -> ff2
    //  buf1: K    -> out1
    //  buf2: V    -> ffh (low half)
    //  buf3: attn -> ffh (high half)
    float* buf0 = ws;
    float* buf1 = buf0 + SZ;
    float* buf2 = buf1 + SZ;
    float* buf3 = buf2 + SZ;

    for (int p = 0; p < 2; ++p) {
        const float* emb_r = p ? col_emb : row_emb;
        const float* emb_c = p ? row_emb : col_emb;
#define PARAM(i) ((const float*)d_in[3 + p * 17 + (i)])
        float* Q    = buf0;
        float* Kb   = buf1;
        float* V    = buf2;
        float* attn = buf3;
        proj_kernel<<<Bc * Nc, 256, 0, stream>>>(emb_r, PARAM(0), Q);
        proj_kernel<<<Bc * Nc, 256, 0, stream>>>(emb_c, PARAM(1), Kb);
        proj_kernel<<<Bc * Nc, 256, 0, stream>>>(emb_c, PARAM(2), V);
        attn_kernel<<<Bc * Hc * Nc, 256, 0, stream>>>(
            Q, Kb, V, cost, PARAM(3), PARAM(4), PARAM(5), PARAM(6), attn, p);
        float* x1 = buf0;   // Q dead
        gemm_kernel<<<Bc * Nc, 256, 256 * 4, stream>>>(
            attn, PARAM(7), PARAM(8), emb_r, x1, 256, 256, 0);
        float* out1 = buf1; // K dead
        inorm_kernel<<<Bc, 256, 0, stream>>>(
            x1, nullptr, PARAM(9), PARAM(10), out1);
        float* ffh = buf2;  // V+attn dead (ffh spans buf2+buf3)
        gemm_kernel<<<Bc * Nc, 512, 256 * 4, stream>>>(
            out1, PARAM(11), PARAM(12), nullptr, ffh, 256, 512, 1);
        float* ff2 = buf0;  // x1 dead
        gemm_kernel<<<Bc * Nc, 256, 512 * 4, stream>>>(
            ffh, PARAM(13), PARAM(14), nullptr, ff2, 512, 256, 0);
        inorm_kernel<<<Bc, 256, 0, stream>>>(
            out1, ff2, PARAM(15), PARAM(16), out + p * SZ);
#undef PARAM
    }
}

// Round 5
// 612.908 us; speedup vs baseline: 1.4170x; 1.4170x over previous
//
#include <hip/hip_runtime.h>
#include <hip/hip_bf16.h>

#define Bc 8
#define Nc 256
#define Dc 256
#define Hc 16
#define DKc 16
#define MSc 16
#define FFc 512

// All tensors (inputs AND output) are fp32 (reference uses jnp.float32).

// Projection emb(b,n,:) @ W -> head layout out[((b*H+h)*N + n)*DK + dk]
__global__ void proj_kernel(const float* __restrict__ emb, const float* __restrict__ W,
                            float* __restrict__ out) {
    int row = blockIdx.x;            // b*N + n
    int b = row >> 8, n = row & 255;
    int hd = threadIdx.x;            // h*DK + dk
    __shared__ float se[Dc];
    se[hd] = emb[row * Dc + hd];
    __syncthreads();
    float acc = 0.f;
#pragma unroll 8
    for (int d = 0; d < Dc; ++d)
        acc += se[d] * W[d * (Hc * DKc) + hd];
    int h = hd >> 4, dk = hd & 15;
    out[((b * Hc + h) * Nc + n) * DKc + dk] = acc;
}

// Fused: dot -> per-head 2->MS->1 MLP -> softmax over cols -> @V
// One block per (b,h,r); thread = column c.
__global__ void attn_kernel(const float* __restrict__ Q, const float* __restrict__ K,
                            const float* __restrict__ V, const float* __restrict__ cost,
                            const float* __restrict__ m1w, const float* __restrict__ m1b,
                            const float* __restrict__ m2w, const float* __restrict__ m2b,
                            float* __restrict__ out_concat, int tr) {
    int idx = blockIdx.x;            // (b*H + h)*N + r
    int r = idx & 255;
    int bh = idx >> 8;
    int h = bh & 15;
    int b = bh >> 4;
    int c = threadIdx.x;

    __shared__ float sq[DKc];
    __shared__ float red[256];
    __shared__ float wsh[256];
    __shared__ float sm1w[32], sm1b[16], sm2w[16], sm2b;

    if (c < DKc) sq[c] = Q[(bh * Nc + r) * DKc + c];
    if (c >= 32 && c < 64)        sm1w[c - 32] = m1w[h * 32 + (c - 32)];
    else if (c >= 64 && c < 80)   sm1b[c - 64] = m1b[h * 16 + (c - 64)];
    else if (c >= 80 && c < 96)   sm2w[c - 80] = m2w[h * 16 + (c - 80)];
    else if (c == 96)             sm2b = m2b[h];
    __syncthreads();

    const float* kp = K + (bh * Nc + c) * DKc;
    float dot = 0.f;
#pragma unroll
    for (int i = 0; i < DKc; ++i) dot += sq[i] * kp[i];
    dot *= 0.25f;  // 1/sqrt(DK)

    float cost_v = tr ? cost[(b * Nc + c) * Nc + r]
                      : cost[(b * Nc + r) * Nc + c];

    float mixed = sm2b;
#pragma unroll
    for (int m = 0; m < MSc; ++m) {
        float t = dot * sm1w[m] + cost_v * sm1w[16 + m] + sm1b[m];
        t = fmaxf(t, 0.f);
        mixed += t * sm2w[m];
    }

    // softmax over the 256 columns
    red[c] = mixed;
    __syncthreads();
    for (int s = 128; s > 0; s >>= 1) {
        if (c < s) red[c] = fmaxf(red[c], red[c + s]);
        __syncthreads();
    }
    float mx = red[0];
    __syncthreads();
    float e = __expf(mixed - mx);
    red[c] = e;
    __syncthreads();
    for (int s = 128; s > 0; s >>= 1) {
        if (c < s) red[c] += red[c + s];
        __syncthreads();
    }
    float w = e / red[0];
    wsh[c] = w;
    __syncthreads();

    // PV: partials over 16-column chunks, then reduce 16 chunks per dk
    int dk = c & 15, chunk = c >> 4;
    const float* vp = V + (bh * Nc + chunk * 16) * DKc + dk;
    float part = 0.f;
#pragma unroll
    for (int j = 0; j < 16; ++j) part += wsh[chunk * 16 + j] * vp[j * DKc];
    red[c] = part;
    __syncthreads();
    if (c < DKc) {
        float o = 0.f;
#pragma unroll
        for (int ch = 0; ch < 16; ++ch) o += red[ch * 16 + c];
        out_concat[(b * Nc + r) * (Hc * DKc) + h * DKc + c] = o;
    }
}

// out[row][j] = sum_k A[row][k]*W[k][j] + bias[j]  (+relu) (+f32 residual)
// blockDim.x == Nout; dynamic LDS = Kdim floats
__global__ void gemm_kernel(const float* __restrict__ A, const float* __restrict__ W,
                            const float* __restrict__ bias, const float* __restrict__ res,
                            float* __restrict__ out, int Kdim, int Nout, int do_relu) {
    int row = blockIdx.x;
    int j = threadIdx.x;
    extern __shared__ float sA[];
    for (int i = j; i < Kdim; i += blockDim.x) sA[i] = A[(size_t)row * Kdim + i];
    __syncthreads();
    float acc = 0.f;
#pragma unroll 8
    for (int k = 0; k < Kdim; ++k) acc += sA[k] * W[k * Nout + j];
    acc += bias[j];
    if (do_relu) acc = fmaxf(acc, 0.f);
    if (res) acc += res[(size_t)row * Nout + j];
    out[(size_t)row * Nout + j] = acc;
}

// Pass 1 of instance norm: per-(b,d) mean & rsqrt(var+eps).
// grid (B, D/64); block 256 = 64 d-lanes x 4 n-groups. Coalesced reads.
__global__ void stats_kernel(const float* __restrict__ x, float* __restrict__ stats) {
    int b = blockIdx.x;
    int dg = blockIdx.y;
    int dl = threadIdx.x & 63;
    int ng = threadIdx.x >> 6;      // 0..3
    int d = dg * 64 + dl;
    const float* xp = x + (size_t)b * Nc * Dc;
    float sum = 0.f, sq = 0.f;
#pragma unroll 4
    for (int i = 0; i < 64; ++i) {
        int n = ng * 64 + i;
        float v = xp[n * Dc + d];
        sum += v;
        sq += v * v;
    }
    __shared__ float ssum[4][64], ssq[4][64];
    ssum[ng][dl] = sum;
    ssq[ng][dl] = sq;
    __syncthreads();
    if (ng == 0) {
        float s = ssum[0][dl] + ssum[1][dl] + ssum[2][dl] + ssum[3][dl];
        float q = ssq[0][dl] + ssq[1][dl] + ssq[2][dl] + ssq[3][dl];
        float mean = s * (1.f / Nc);
        float var = q * (1.f / Nc) - mean * mean;
        stats[(b * Dc + d) * 2]     = mean;
        stats[(b * Dc + d) * 2 + 1] = rsqrtf(var + 1e-5f);
    }
}

// Pass 2: elementwise normalize. grid B*N, block 256 (one thread per d).
__global__ void apply_kernel(const float* __restrict__ x, const float* __restrict__ stats,
                             const float* __restrict__ scale, const float* __restrict__ bias,
                             float* __restrict__ out) {
    int row = blockIdx.x;            // b*N + n
    int b = row >> 8;
    int d = threadIdx.x;
    float v = x[(size_t)row * Dc + d];
    float mean = stats[(b * Dc + d) * 2];
    float inv  = stats[(b * Dc + d) * 2 + 1];
    out[(size_t)row * Dc + d] = (v - mean) * inv * scale[d] + bias[d];
}

extern "C" void kernel_launch(void* const* d_in, const int* in_sizes, int n_in,
                              void* d_out, int out_size, void* d_ws, size_t ws_size,
                              hipStream_t stream) {
    const float* row_emb = (const float*)d_in[0];
    const float* col_emb = (const float*)d_in[1];
    const float* cost    = (const float*)d_in[2];
    float* out = (float*)d_out;
    float* ws = (float*)d_ws;

    const size_t SZ = (size_t)Bc * Nc * Dc;   // 524288
    // Buffers (4*SZ floats = 8.39 MB + 16 KB stats):
    //  buf0: Q    -> x1  -> ff2(+out1 residual fused)
    //  buf1: K    -> out1
    //  buf2: V    -> ffh (low half)
    //  buf3: attn -> ffh (high half)
    float* buf0 = ws;
    float* buf1 = buf0 + SZ;
    float* buf2 = buf1 + SZ;
    float* buf3 = buf2 + SZ;
    float* stats = buf3 + SZ;        // B*D*2 = 4096 floats

    for (int p = 0; p < 2; ++p) {
        const float* emb_r = p ? col_emb : row_emb;
        const float* emb_c = p ? row_emb : col_emb;
#define PARAM(i) ((const float*)d_in[3 + p * 17 + (i)])
        float* Q    = buf0;
        float* Kb   = buf1;
        float* V    = buf2;
        float* attn = buf3;
        proj_kernel<<<Bc * Nc, 256, 0, stream>>>(emb_r, PARAM(0), Q);
        proj_kernel<<<Bc * Nc, 256, 0, stream>>>(emb_c, PARAM(1), Kb);
        proj_kernel<<<Bc * Nc, 256, 0, stream>>>(emb_c, PARAM(2), V);
        attn_kernel<<<Bc * Hc * Nc, 256, 0, stream>>>(
            Q, Kb, V, cost, PARAM(3), PARAM(4), PARAM(5), PARAM(6), attn, p);
        // x1 = attn @ cw + cb + emb_r   (residual fused into epilogue)
        float* x1 = buf0;   // Q dead
        gemm_kernel<<<Bc * Nc, 256, 256 * 4, stream>>>(
            attn, PARAM(7), PARAM(8), emb_r, x1, 256, 256, 0);
        // out1 = inorm(x1)  [two-pass]
        float* out1 = buf1; // K dead
        stats_kernel<<<dim3(Bc, Dc / 64), 256, 0, stream>>>(x1, stats);
        apply_kernel<<<Bc * Nc, 256, 0, stream>>>(x1, stats, PARAM(9), PARAM(10), out1);
        // ffh = relu(out1 @ w1 + b1)
        float* ffh = buf2;  // V+attn dead (ffh spans buf2+buf3)
        gemm_kernel<<<Bc * Nc, 512, 256 * 4, stream>>>(
            out1, PARAM(11), PARAM(12), nullptr, ffh, 256, 512, 1);
        // ff2' = ffh @ w2 + b2 + out1   (second residual fused here)
        float* ff2 = buf0;  // x1 dead
        gemm_kernel<<<Bc * Nc, 256, 512 * 4, stream>>>(
            ffh, PARAM(13), PARAM(14), out1, ff2, 512, 256, 0);
        // out = inorm(ff2')  [two-pass]
        stats_kernel<<<dim3(Bc, Dc / 64), 256, 0, stream>>>(ff2, stats);
        apply_kernel<<<Bc * Nc, 256, 0, stream>>>(
            ff2, stats, PARAM(15), PARAM(16), out + p * SZ);
#undef PARAM
    }
}